// Round 1
// baseline (220.566 us; speedup 1.0000x reference)
//
#include <hip/hip_runtime.h>
#include <hip/hip_bf16.h>

typedef __bf16 bf16_t;
typedef __bf16 bf16x8 __attribute__((ext_vector_type(8)));
typedef __bf16 bf16x4 __attribute__((ext_vector_type(4)));
typedef float  f32x4  __attribute__((ext_vector_type(4)));

#define NGRAPH 128
#define NPG    512            // nodes per graph
#define CIN    512            // C (K dim)
#define NHEAD  8
#define HID    256            // N dim of layer-1 GEMM

// ---------------------------------------------------------------------------
// Prep: W1 [8][512][256] f32  ->  W1T [8][256][512] bf16 (transposed so the
// MFMA B-operand fragment (n=lane&15, k contiguous) is a ds_read_b128).
// ---------------------------------------------------------------------------
__global__ __launch_bounds__(256) void prep_w1(const float* __restrict__ W1,
                                               bf16_t* __restrict__ W1T) {
  __shared__ float tile[64][65];          // +1 pad breaks bank conflicts
  const int n0 = blockIdx.x * 64;         // 4 tiles over HID
  const int k0 = blockIdx.y * 64;         // 8 tiles over C
  const int h  = blockIdx.z;              // 8 heads
  const int tid = threadIdx.x;
  const int r = tid >> 4, c4 = tid & 15;
  const float* src = W1 + (((size_t)h * CIN + k0) * HID + n0);
#pragma unroll
  for (int i = 0; i < 4; i++) {
    const int rr = r + i * 16;            // k-row within tile
    const float4 v = *(const float4*)(src + (size_t)rr * HID + c4 * 4);
    tile[rr][c4 * 4 + 0] = v.x; tile[rr][c4 * 4 + 1] = v.y;
    tile[rr][c4 * 4 + 2] = v.z; tile[rr][c4 * 4 + 3] = v.w;
  }
  __syncthreads();
  bf16_t* dst = W1T + (((size_t)h * HID + n0) * CIN + k0);
#pragma unroll
  for (int i = 0; i < 2; i++) {
    const int u = tid + i * 256;
    const int n = u >> 3, kc = u & 7;     // 64 n-rows x 8 chunks of 8 bf16
    bf16x8 o;
#pragma unroll
    for (int j = 0; j < 8; j++) o[j] = (bf16_t)tile[kc * 8 + j][n];
    *(bf16x8*)(dst + (size_t)n * CIN + kc * 8) = o;
  }
}

// ---------------------------------------------------------------------------
// Main fused kernel: per block = one 64-node slice of one graph.
// Layer 1 (64x256 = 4 waves x 64x64 of 16x16x32 bf16 MFMA) + bias + SiLU +
// layer-2 dot with W2[head] fused in the epilogue.
// ---------------------------------------------------------------------------
__global__ __launch_bounds__(256, 2) void energy_main(
    const float* __restrict__ x, const int* __restrict__ task,
    const bf16_t* __restrict__ W1T, const float* __restrict__ b1,
    const float* __restrict__ W2, const float* __restrict__ b2,
    float* __restrict__ out) {
  // stride 72 bf16 = 36 dwords -> worst 2-way bank aliasing on b128 reads (free)
  __shared__ bf16_t As[64][72];
  __shared__ bf16_t Bs[256][72];
  __shared__ float  red[4][64];

  const int bx   = blockIdx.x;
  const int g    = bx >> 3;               // graph
  const int mt   = bx & 7;                // M-tile within graph
  const int head = task[g];
  const int base = g * NPG + mt * 64;     // first node of this block
  const int tid  = threadIdx.x;
  const int wave = tid >> 6, lane = tid & 63;
  const int q = lane >> 4, t = lane & 15;

  const float*  Ag = x + (size_t)base * CIN;
  const bf16_t* Bg = W1T + (size_t)head * HID * CIN;

  f32x4 acc[4][4] = {};

  const int a_row = tid >> 4, a_c4 = tid & 15;  // A: 64 rows x 16 float4 chunks
  const int b_n   = tid >> 3, b_kc = tid & 7;   // B: 256 rows x 8 bf16x8 chunks

  for (int k0 = 0; k0 < CIN; k0 += 64) {
    if (k0) __syncthreads();              // previous MFMA reads done
    // ---- stage A tile (fp32 -> bf16) : 64 x 64
#pragma unroll
    for (int j = 0; j < 4; j++) {
      const int row = a_row + j * 16;
      const float4 v = *(const float4*)(Ag + (size_t)row * CIN + k0 + a_c4 * 4);
      bf16x4 bv;
      bv[0] = (bf16_t)v.x; bv[1] = (bf16_t)v.y;
      bv[2] = (bf16_t)v.z; bv[3] = (bf16_t)v.w;
      *(bf16x4*)&As[row][a_c4 * 4] = bv;
    }
    // ---- stage B tile (bf16 copy) : 256 x 64
#pragma unroll
    for (int j = 0; j < 8; j++) {
      const int n = b_n + j * 32;
      *(bf16x8*)&Bs[n][b_kc * 8] =
          *(const bf16x8*)(Bg + (size_t)n * CIN + k0 + b_kc * 8);
    }
    __syncthreads();
    // ---- MFMA: 2 K-steps of 32
#pragma unroll
    for (int ks = 0; ks < 64; ks += 32) {
      bf16x8 af[4], bfr[4];
#pragma unroll
      for (int mi = 0; mi < 4; mi++)
        af[mi] = *(const bf16x8*)&As[mi * 16 + t][ks + q * 8];
#pragma unroll
      for (int ni = 0; ni < 4; ni++)
        bfr[ni] = *(const bf16x8*)&Bs[wave * 64 + ni * 16 + t][ks + q * 8];
#pragma unroll
      for (int mi = 0; mi < 4; mi++)
#pragma unroll
        for (int ni = 0; ni < 4; ni++)
          acc[mi][ni] = __builtin_amdgcn_mfma_f32_16x16x32_bf16(
              af[mi], bfr[ni], acc[mi][ni], 0, 0, 0);
    }
  }

  // ---- fused epilogue: h = silu(acc + b1[head]); y = h . W2[head] + b2[head]
  // C/D layout: col(n) = t (+tile offsets), row(m) = q*4 + r (+mi*16)
  float w2c[4], b1c[4];
#pragma unroll
  for (int ni = 0; ni < 4; ni++) {
    const int col = wave * 64 + ni * 16 + t;
    w2c[ni] = W2[head * HID + col];
    b1c[ni] = b1[head * HID + col];
  }
  float part[4][4];
#pragma unroll
  for (int mi = 0; mi < 4; mi++)
#pragma unroll
    for (int r = 0; r < 4; r++) {
      float s = 0.f;
#pragma unroll
      for (int ni = 0; ni < 4; ni++) {
        const float hh = acc[mi][ni][r] + b1c[ni];
        s += (hh / (1.f + __expf(-hh))) * w2c[ni];   // silu(hh) * w2
      }
      part[mi][r] = s;
    }
  // reduce across the 16 lanes holding the 16 cols of each 16-wide tile slice
#pragma unroll
  for (int off = 1; off < 16; off <<= 1)
#pragma unroll
    for (int mi = 0; mi < 4; mi++)
#pragma unroll
      for (int r = 0; r < 4; r++)
        part[mi][r] += __shfl_xor(part[mi][r], off, 64);
  if (t == 0) {
#pragma unroll
    for (int mi = 0; mi < 4; mi++)
#pragma unroll
      for (int r = 0; r < 4; r++)
        red[wave][mi * 16 + q * 4 + r] = part[mi][r];
  }
  __syncthreads();
  if (tid < 64) {
    const float y = red[0][tid] + red[1][tid] + red[2][tid] + red[3][tid] +
                    b2[head];
    out[base + tid] = y;
  }
}

extern "C" void kernel_launch(void* const* d_in, const int* in_sizes, int n_in,
                              void* d_out, int out_size, void* d_ws,
                              size_t ws_size, hipStream_t stream) {
  const float* x    = (const float*)d_in[0];   // [65536,512] f32
  // d_in[1] = n_node (all 512) — graph boundaries are fixed 512-node blocks
  const int*   task = (const int*)d_in[2];     // [128] i32
  const float* W1   = (const float*)d_in[3];   // [8,512,256] f32
  const float* b1   = (const float*)d_in[4];   // [8,256] f32
  const float* W2   = (const float*)d_in[5];   // [8,256,1] f32
  const float* b2   = (const float*)d_in[6];   // [8,1] f32
  float* out = (float*)d_out;                  // [65536,1] f32

  bf16_t* W1T = (bf16_t*)d_ws;                 // 8*256*512*2 = 2 MB scratch

  prep_w1<<<dim3(4, 8, 8), 256, 0, stream>>>(W1, W1T);
  energy_main<<<dim3(NGRAPH * 8), 256, 0, stream>>>(x, task, W1T, b1, W2, b2,
                                                    out);
}

// Round 2
// 214.126 us; speedup vs baseline: 1.0301x; 1.0301x over previous
//
#include <hip/hip_runtime.h>
#include <hip/hip_bf16.h>
#include <stdint.h>

typedef __bf16 bf16_t;
typedef __bf16 bf16x8 __attribute__((ext_vector_type(8)));
typedef float  f32x4  __attribute__((ext_vector_type(4)));

#define NGRAPH 128
#define NPG    512            // nodes per graph
#define CIN    512            // K dim
#define HID    256            // N dim of layer-1 GEMM
#define BM     128            // M tile per block
#define BK     64             // K tile

// async 16B global -> LDS (wave-uniform base + lane*16 ordering required)
__device__ __forceinline__ void gl2lds16(const void* g, void* l) {
  __builtin_amdgcn_global_load_lds(
      (const __attribute__((address_space(1))) uint32_t*)g,
      (__attribute__((address_space(3))) uint32_t*)l, 16, 0, 0);
}

// ---------------------------------------------------------------------------
// Prep: W1 [8][512][256] f32 -> Bimg: per (head, ktile) a 32 KB LDS-image of
// the 256(n) x 64(k) bf16 B-tile, XOR-swizzled: slot (n, c') holds k-chunk
// c = c' ^ (n&7) (8 bf16 each). Main kernel then stages B with pure-linear
// global_load_lds and gets conflict-free ds_read_b128 fragments.
// ---------------------------------------------------------------------------
__global__ __launch_bounds__(256) void prep_w1(const float* __restrict__ W1,
                                               bf16_t* __restrict__ Bimg) {
  __shared__ float tile[64][65];          // [k][n], +1 pad
  const int n0 = blockIdx.x * 64;         // 4 tiles over HID
  const int kt = blockIdx.y;              // 8 tiles over CIN
  const int h  = blockIdx.z;              // 8 heads
  const int k0 = kt * 64;
  const int tid = threadIdx.x;
  const int r = tid >> 4, c4 = tid & 15;
  const float* src = W1 + (((size_t)h * CIN + k0) * HID + n0);
#pragma unroll
  for (int i = 0; i < 4; i++) {
    const int rr = r + i * 16;
    const float4 v = *(const float4*)(src + (size_t)rr * HID + c4 * 4);
    tile[rr][c4 * 4 + 0] = v.x; tile[rr][c4 * 4 + 1] = v.y;
    tile[rr][c4 * 4 + 2] = v.z; tile[rr][c4 * 4 + 3] = v.w;
  }
  __syncthreads();
  bf16_t* dst = Bimg + (size_t)(h * 8 + kt) * 16384;
#pragma unroll
  for (int i = 0; i < 2; i++) {
    const int u = tid + i * 256;
    const int n = u >> 3, c = u & 7;      // n within tile, data k-chunk c
    bf16x8 o;
#pragma unroll
    for (int j = 0; j < 8; j++) o[j] = (bf16_t)tile[c * 8 + j][n];
    const int ng = n0 + n;
    const int cp = c ^ (ng & 7);          // swizzled slot
    *(bf16x8*)(dst + (size_t)ng * 64 + cp * 8) = o;
  }
}

// ---------------------------------------------------------------------------
// Main fused kernel: block = 128-node slice of one graph. 4 waves partition
// HID into 64-wide slices; each wave: 8(mi) x 4(ni) tiles of 16x16x32 bf16.
// A staged as raw fp32 via global_load_lds (XOR-swizzled source), converted
// to bf16 at fragment-load. B staged linear from the pre-swizzled image.
// Epilogue fuses bias + SiLU + dot(W2) + b2.
// ---------------------------------------------------------------------------
__global__ __launch_bounds__(256, 2) void energy_main(
    const float* __restrict__ x, const int* __restrict__ task,
    const bf16_t* __restrict__ Bimg, const float* __restrict__ b1,
    const float* __restrict__ W2, const float* __restrict__ b2,
    float* __restrict__ out) {
  __shared__ float  As[BM * BK];          // 32 KB, swizzled fp32 image
  __shared__ bf16_t Bs[HID * BK];         // 32 KB, swizzled bf16 image
  __shared__ float  red[4][BM];           // 2 KB

  const int bx   = blockIdx.x;
  const int g    = bx >> 2;               // graph
  const int mt   = bx & 3;                // M-tile within graph
  const int head = task[g];
  const int base = g * NPG + mt * BM;
  const int tid  = threadIdx.x;
  const int wave = tid >> 6, lane = tid & 63;
  const int q = lane >> 4, t = lane & 15;

  const float*  Ag = x + (size_t)base * CIN;
  const bf16_t* Bh = Bimg + (size_t)head * 8 * 16384;

  const int a_row16 = tid >> 4;           // row = j*16 + a_row16
  const int a_cp    = tid & 15;           // slot chunk (16 B)

  f32x4 acc[8][4] = {};

  for (int kt = 0; kt < 8; kt++) {
    const int k0 = kt * 64;
    if (kt) __syncthreads();              // prior MFMA reads done
    // ---- A: 8 async issues, 4 KB each (raw fp32, swizzled source chunk)
#pragma unroll
    for (int j = 0; j < 8; j++) {
      const int row = j * 16 + a_row16;
      const int c = a_cp ^ (row & 7);     // data chunk for this slot
      gl2lds16(Ag + (size_t)row * CIN + k0 + c * 4, As + j * 1024 + tid * 4);
    }
    // ---- B: 8 async issues, pure linear copy of pre-swizzled image
    const bf16_t* Bt = Bh + (size_t)kt * 16384;
#pragma unroll
    for (int j = 0; j < 8; j++)
      gl2lds16(Bt + j * 2048 + tid * 8, Bs + j * 2048 + tid * 8);
    __syncthreads();                      // drains vmcnt (loads landed)

#pragma unroll
    for (int ks = 0; ks < 64; ks += 32) {
      bf16x8 bfr[4];
#pragma unroll
      for (int ni = 0; ni < 4; ni++) {
        const int n = wave * 64 + ni * 16 + t;
        const int cp = (ks / 8 + q) ^ (n & 7);
        bfr[ni] = *(const bf16x8*)(Bs + n * 64 + cp * 8);
      }
#pragma unroll
      for (int mi = 0; mi < 8; mi++) {
        const int row = mi * 16 + t;
        const int s = row & 7;
        const int c0 = ks / 4 + q * 2;    // even
        const float4 v0 = *(const float4*)(As + row * 64 + ((c0) ^ s) * 4);
        const float4 v1 = *(const float4*)(As + row * 64 + ((c0 + 1) ^ s) * 4);
        bf16x8 af;
        af[0] = (bf16_t)v0.x; af[1] = (bf16_t)v0.y;
        af[2] = (bf16_t)v0.z; af[3] = (bf16_t)v0.w;
        af[4] = (bf16_t)v1.x; af[5] = (bf16_t)v1.y;
        af[6] = (bf16_t)v1.z; af[7] = (bf16_t)v1.w;
#pragma unroll
        for (int ni = 0; ni < 4; ni++)
          acc[mi][ni] = __builtin_amdgcn_mfma_f32_16x16x32_bf16(
              af, bfr[ni], acc[mi][ni], 0, 0, 0);
      }
    }
  }

  // ---- fused epilogue: y = silu(acc + b1) . W2 + b2
  // C/D layout: col(n) = t (+tiles), row(m) = q*4 + r (+mi*16)
  float w2c[4], b1c[4];
#pragma unroll
  for (int ni = 0; ni < 4; ni++) {
    const int col = wave * 64 + ni * 16 + t;
    w2c[ni] = W2[head * HID + col];
    b1c[ni] = b1[head * HID + col];
  }
  float part[8][4];
#pragma unroll
  for (int mi = 0; mi < 8; mi++)
#pragma unroll
    for (int r = 0; r < 4; r++) {
      float sacc = 0.f;
#pragma unroll
      for (int ni = 0; ni < 4; ni++) {
        const float hh = acc[mi][ni][r] + b1c[ni];
        sacc += (hh / (1.f + __expf(-hh))) * w2c[ni];   // silu * w2
      }
      part[mi][r] = sacc;
    }
#pragma unroll
  for (int off = 1; off < 16; off <<= 1)
#pragma unroll
    for (int mi = 0; mi < 8; mi++)
#pragma unroll
      for (int r = 0; r < 4; r++)
        part[mi][r] += __shfl_xor(part[mi][r], off, 64);
  if (t == 0) {
#pragma unroll
    for (int mi = 0; mi < 8; mi++)
#pragma unroll
      for (int r = 0; r < 4; r++)
        red[wave][mi * 16 + q * 4 + r] = part[mi][r];
  }
  __syncthreads();
  if (tid < BM) {
    out[base + tid] = red[0][tid] + red[1][tid] + red[2][tid] + red[3][tid] +
                      b2[head];
  }
}

extern "C" void kernel_launch(void* const* d_in, const int* in_sizes, int n_in,
                              void* d_out, int out_size, void* d_ws,
                              size_t ws_size, hipStream_t stream) {
  const float* x    = (const float*)d_in[0];   // [65536,512] f32
  // d_in[1] = n_node (all 512): fixed 512-node graphs
  const int*   task = (const int*)d_in[2];     // [128] i32
  const float* W1   = (const float*)d_in[3];   // [8,512,256] f32
  const float* b1   = (const float*)d_in[4];   // [8,256] f32
  const float* W2   = (const float*)d_in[5];   // [8,256,1] f32
  const float* b2   = (const float*)d_in[6];   // [8,1] f32
  float* out = (float*)d_out;                  // [65536] f32

  bf16_t* Bimg = (bf16_t*)d_ws;                // 2 MB swizzled W1 image

  prep_w1<<<dim3(4, 8, 8), 256, 0, stream>>>(W1, Bimg);
  energy_main<<<dim3(NGRAPH * 4), 256, 0, stream>>>(x, task, Bimg, b1, W2, b2,
                                                    out);
}